// Round 1
// baseline (711.338 us; speedup 1.0000x reference)
//
#include <hip/hip_runtime.h>
#include <stdint.h>

#define B_ 64
#define S_ 512
#define K_ 1024
#define H_ 4096
#define C_ 32

typedef float  f32x4  __attribute__((ext_vector_type(4)));
typedef short  bf16x8 __attribute__((ext_vector_type(8)));
typedef unsigned short u16x8 __attribute__((ext_vector_type(8)));
typedef __attribute__((address_space(3))) unsigned int as3u32;
typedef const __attribute__((address_space(1))) unsigned int as1u32;

__device__ __forceinline__ unsigned short f2bf(float f) {
    unsigned u = __builtin_bit_cast(unsigned, f);
    u += 0x7fffu + ((u >> 16) & 1u);   // RNE
    return (unsigned short)(u >> 16);
}

// ---------------------------------------------------------------------------
// cat_ids may arrive as int32 or int64; detect on-device and normalize to i32.
// One wave. If the int64 interpretation of the first 32 entries is all in
// [0,32), data is int64 (high words of true int32 data are ~never all zero).
__global__ void fix_cat_kernel(const void* __restrict__ cat_raw, int* __restrict__ cat32) {
    int t = threadIdx.x;                       // 64 threads = 1 wave
    const long long* c64 = (const long long*)cat_raw;
    const int*       c32 = (const int*)cat_raw;
    long long v = (t < 32) ? c64[t] : 0;
    int bad = (t < 32) && (v < 0 || v >= C_);
    unsigned long long m = __ballot(bad);
    if (m == 0ULL) {
        cat32[t] = (int)c64[t];
    } else {
        cat32[t] = c32[t];
    }
}

// ---------------------------------------------------------------------------
// x f32 -> bf16, vectorized 8 elems/thread
__global__ __launch_bounds__(256) void cvt_x_kernel(const float4* __restrict__ x,
                                                    uint4* __restrict__ xb, int n8) {
    int stride = gridDim.x * blockDim.x;
    for (int i = blockIdx.x * blockDim.x + threadIdx.x; i < n8; i += stride) {
        float4 a = x[2 * i], b = x[2 * i + 1];
        uint4 o;
        o.x = (unsigned)f2bf(a.x) | ((unsigned)f2bf(a.y) << 16);
        o.y = (unsigned)f2bf(a.z) | ((unsigned)f2bf(a.w) << 16);
        o.z = (unsigned)f2bf(b.x) | ((unsigned)f2bf(b.y) << 16);
        o.w = (unsigned)f2bf(b.z) | ((unsigned)f2bf(b.w) << 16);
        xb[i] = o;
    }
}

// ---------------------------------------------------------------------------
// W [C][K][H] f32 -> WT [C][H][K] bf16, LDS-tiled 64x64 transpose
__global__ __launch_bounds__(256) void cvt_w_kernel(const float* __restrict__ W,
                                                    unsigned short* __restrict__ WT) {
    __shared__ unsigned short tile[64 * 68];   // [k][n], padded stride 68
    const int nt = blockIdx.x;                 // 64 n-tiles
    const int kt = blockIdx.y;                 // 16 k-tiles
    const int c  = blockIdx.z;                 // 32 categories
    const int t  = threadIdx.x;

    const float* Wp = W + ((size_t)c << 22);   // c * K_*H_ = c * 2^22
#pragma unroll
    for (int p = 0; p < 4; ++p) {
        int task = p * 256 + t;                // 0..1023
        int kr = task >> 4;                    // 0..63
        int nc = (task & 15) << 2;             // 0..60
        float4 v = *(const float4*)(Wp + (size_t)(kt * 64 + kr) * H_ + nt * 64 + nc);
        tile[kr * 68 + nc + 0] = f2bf(v.x);
        tile[kr * 68 + nc + 1] = f2bf(v.y);
        tile[kr * 68 + nc + 2] = f2bf(v.z);
        tile[kr * 68 + nc + 3] = f2bf(v.w);
    }
    __syncthreads();

    unsigned short* WTp = WT + ((size_t)c << 22);
#pragma unroll
    for (int q = 0; q < 2; ++q) {
        int task = q * 256 + t;                // 0..511
        int nl = task >> 3;                    // 0..63
        int ko = (task & 7) << 3;              // 0,8,..,56
        u16x8 o;
#pragma unroll
        for (int j = 0; j < 8; ++j) o[j] = tile[(ko + j) * 68 + nl];
        *(u16x8*)(WTp + (size_t)(nt * 64 + nl) * K_ + kt * 64 + ko) = o;
    }
}

// ---------------------------------------------------------------------------
// Batched GEMM, m97 structure: 128x128x64 tile, 4 waves (2x2), 16x16x32 bf16
// MFMA 4x4 frags/wave, global_load_lds width-16 linear staging, 2 barriers/K.
__global__ __launch_bounds__(256) void gemm_kernel(
    const unsigned short* __restrict__ xb,   // [B][S][K] bf16
    const unsigned short* __restrict__ WT,   // [C][H][K] bf16
    const float* __restrict__ bias,          // [C][H]
    const int* __restrict__ cat,             // [B]
    float* __restrict__ out)                 // [B][S][H]
{
    __shared__ __align__(16) unsigned short As[128 * 64];  // [m][k]
    __shared__ __align__(16) unsigned short Bs[128 * 64];  // [n][k]

    const int t    = threadIdx.x;
    const int lane = t & 63;
    const int w    = t >> 6;
    const int wm   = w >> 1, wn = w & 1;
    const int lo   = lane & 15, hi = lane >> 4;

    const int blk = blockIdx.x;              // bb*128 + tm*32 + tn
    const int tn  = blk & 31;
    const int tm  = (blk >> 5) & 3;
    const int bb  = blk >> 7;

    const int c = cat[bb];

    const unsigned short* Ag0 = xb + (size_t)bb * (S_ * K_) + (size_t)(tm * 128) * K_;
    const unsigned short* Bg0 = WT + (size_t)c * ((size_t)H_ * K_) + (size_t)(tn * 128) * K_;

    const int r_st  = lane >> 3;             // staging row within chunk
    const int cb_el = (lane & 7) * 8;        // element offset (16B per lane)

    f32x4 acc[4][4];
#pragma unroll
    for (int i = 0; i < 4; ++i)
#pragma unroll
        for (int j = 0; j < 4; ++j) acc[i][j] = f32x4{0.f, 0.f, 0.f, 0.f};

    for (int kt = 0; kt < K_ / 64; ++kt) {
        const unsigned short* Ag = Ag0 + kt * 64;
        const unsigned short* Bg = Bg0 + kt * 64;
#pragma unroll
        for (int i = 0; i < 4; ++i) {
            int ch = w * 4 + i;              // wave-uniform chunk id
            int r  = ch * 8 + r_st;
            __builtin_amdgcn_global_load_lds((as1u32*)(Ag + (size_t)r * K_ + cb_el),
                                             (as3u32*)(As + ch * 512), 16, 0, 0);
            __builtin_amdgcn_global_load_lds((as1u32*)(Bg + (size_t)r * K_ + cb_el),
                                             (as3u32*)(Bs + ch * 512), 16, 0, 0);
        }
        asm volatile("s_waitcnt vmcnt(0)" ::: "memory");
        __syncthreads();

#pragma unroll
        for (int ks = 0; ks < 2; ++ks) {
            bf16x8 av[4], bv[4];
#pragma unroll
            for (int mi = 0; mi < 4; ++mi) {
                int row = wm * 64 + mi * 16 + lo;
                av[mi] = *(const bf16x8*)((const char*)As + row * 128 + ks * 64 + hi * 16);
            }
#pragma unroll
            for (int ni = 0; ni < 4; ++ni) {
                int row = wn * 64 + ni * 16 + lo;
                bv[ni] = *(const bf16x8*)((const char*)Bs + row * 128 + ks * 64 + hi * 16);
            }
#pragma unroll
            for (int mi = 0; mi < 4; ++mi)
#pragma unroll
                for (int ni = 0; ni < 4; ++ni)
                    acc[mi][ni] = __builtin_amdgcn_mfma_f32_16x16x32_bf16(
                        av[mi], bv[ni], acc[mi][ni], 0, 0, 0);
        }
        __syncthreads();
    }

    // epilogue: + bias, scalar f32 stores (C/D: col=lane&15, row=(lane>>4)*4+r)
    const size_t ob = (size_t)bb * S_ * H_;
#pragma unroll
    for (int ni = 0; ni < 4; ++ni) {
        int n_g = tn * 128 + wn * 64 + ni * 16 + lo;
        float bvv = bias[c * H_ + n_g];
#pragma unroll
        for (int mi = 0; mi < 4; ++mi) {
            int m0 = tm * 128 + wm * 64 + mi * 16 + hi * 4;
#pragma unroll
            for (int r = 0; r < 4; ++r)
                out[ob + (size_t)(m0 + r) * H_ + n_g] = acc[mi][ni][r] + bvv;
        }
    }
}

// ---------------------------------------------------------------------------
// Fallback (ws too small): correct but slow f32 vector-ALU kernel.
__global__ __launch_bounds__(256) void fallback_kernel(
    const float* __restrict__ x, const int* __restrict__ cat,
    const float* __restrict__ W, const float* __restrict__ bias,
    float* __restrict__ out)
{
    __shared__ float xs[K_];
    int bs = blockIdx.x;                     // b*512 + s
    int bb = bs >> 9;
    int c  = cat[bb];
    const float* xp = x + (size_t)bs * K_;
    for (int i = threadIdx.x; i < K_ / 4; i += 256)
        ((float4*)xs)[i] = ((const float4*)xp)[i];
    __syncthreads();

    int h = blockIdx.y * 1024 + threadIdx.x * 4;
    const float* Wp = W + (size_t)c * K_ * H_ + h;
    float a0 = 0.f, a1 = 0.f, a2 = 0.f, a3 = 0.f;
    for (int k = 0; k < K_; ++k) {
        float xv = xs[k];
        float4 wv = *(const float4*)(Wp + (size_t)k * H_);
        a0 += xv * wv.x; a1 += xv * wv.y; a2 += xv * wv.z; a3 += xv * wv.w;
    }
    float4 bv = *(const float4*)(bias + c * H_ + h);
    float4 o; o.x = a0 + bv.x; o.y = a1 + bv.y; o.z = a2 + bv.z; o.w = a3 + bv.w;
    *(float4*)(out + (size_t)bs * H_ + h) = o;
}

// ---------------------------------------------------------------------------
extern "C" void kernel_launch(void* const* d_in, const int* in_sizes, int n_in,
                              void* d_out, int out_size, void* d_ws, size_t ws_size,
                              hipStream_t stream) {
    const float* x        = (const float*)d_in[0];
    const void*  cat_raw  = d_in[1];
    const float* W        = (const float*)d_in[2];
    const float* bias     = (const float*)d_in[3];
    float*       out      = (float*)d_out;

    const size_t CAT_BYTES = 256;
    const size_t XB_OFF    = 256;
    const size_t XB_BYTES  = (size_t)B_ * S_ * K_ * 2;          // 64 MiB
    const size_t WT_OFF    = XB_OFF + XB_BYTES;
    const size_t WT_BYTES  = (size_t)C_ * H_ * K_ * 2;          // 256 MiB
    const size_t NEED      = WT_OFF + WT_BYTES;

    const int* catp;
    if (ws_size >= CAT_BYTES) {
        int* cat32 = (int*)d_ws;
        fix_cat_kernel<<<1, 64, 0, stream>>>(cat_raw, cat32);
        catp = cat32;
    } else {
        catp = (const int*)cat_raw;
    }

    if (ws_size >= NEED) {
        unsigned short* xb = (unsigned short*)((char*)d_ws + XB_OFF);
        unsigned short* WT = (unsigned short*)((char*)d_ws + WT_OFF);
        cvt_x_kernel<<<2048, 256, 0, stream>>>((const float4*)x, (uint4*)xb,
                                               (int)((size_t)B_ * S_ * K_ / 8));
        dim3 gw(64, 16, 32);
        cvt_w_kernel<<<gw, 256, 0, stream>>>(W, WT);
        gemm_kernel<<<B_ * 4 * 32, 256, 0, stream>>>(xb, WT, bias, catp, out);
    } else {
        dim3 g(B_ * S_, H_ / 1024);
        fallback_kernel<<<g, 256, 0, stream>>>(x, catp, W, bias, out);
    }
}

// Round 2
// 566.204 us; speedup vs baseline: 1.2563x; 1.2563x over previous
//
#include <hip/hip_runtime.h>
#include <stdint.h>

#define B_ 64
#define S_ 512
#define K_ 1024
#define H_ 4096
#define C_ 32

typedef float  f32x4  __attribute__((ext_vector_type(4)));
typedef short  bf16x8 __attribute__((ext_vector_type(8)));
typedef unsigned short u16x8 __attribute__((ext_vector_type(8)));
typedef __attribute__((address_space(3))) unsigned int as3u32;
typedef const __attribute__((address_space(1))) unsigned int as1u32;

__device__ __forceinline__ unsigned short f2bf(float f) {
    unsigned u = __builtin_bit_cast(unsigned, f);
    u += 0x7fffu + ((u >> 16) & 1u);   // RNE
    return (unsigned short)(u >> 16);
}

// ---------------------------------------------------------------------------
// cat_ids may arrive as int32 or int64; detect on-device, normalize to i32.
__global__ void fix_cat_kernel(const void* __restrict__ cat_raw, int* __restrict__ cat32) {
    int t = threadIdx.x;                       // 64 threads = 1 wave
    const long long* c64 = (const long long*)cat_raw;
    const int*       c32 = (const int*)cat_raw;
    long long v = (t < 32) ? c64[t] : 0;
    int bad = (t < 32) && (v < 0 || v >= C_);
    unsigned long long m = __ballot(bad);
    if (m == 0ULL) {
        cat32[t] = (int)c64[t];
    } else {
        cat32[t] = c32[t];
    }
}

// ---------------------------------------------------------------------------
// x f32 -> bf16, vectorized 8 elems/thread
__global__ __launch_bounds__(256) void cvt_x_kernel(const float4* __restrict__ x,
                                                    uint4* __restrict__ xb, int n8) {
    int stride = gridDim.x * blockDim.x;
    for (int i = blockIdx.x * blockDim.x + threadIdx.x; i < n8; i += stride) {
        float4 a = x[2 * i], b = x[2 * i + 1];
        uint4 o;
        o.x = (unsigned)f2bf(a.x) | ((unsigned)f2bf(a.y) << 16);
        o.y = (unsigned)f2bf(a.z) | ((unsigned)f2bf(a.w) << 16);
        o.z = (unsigned)f2bf(b.x) | ((unsigned)f2bf(b.y) << 16);
        o.w = (unsigned)f2bf(b.z) | ((unsigned)f2bf(b.w) << 16);
        xb[i] = o;
    }
}

// ---------------------------------------------------------------------------
// W [C][K][H] f32 -> WT [C][H][K] bf16, LDS-tiled 64x64 transpose
__global__ __launch_bounds__(256) void cvt_w_kernel(const float* __restrict__ W,
                                                    unsigned short* __restrict__ WT) {
    __shared__ unsigned short tile[64 * 68];   // [k][n], padded stride 68
    const int nt = blockIdx.x;                 // 64 n-tiles
    const int kt = blockIdx.y;                 // 16 k-tiles
    const int c  = blockIdx.z;                 // 32 categories
    const int t  = threadIdx.x;

    const float* Wp = W + ((size_t)c << 22);
#pragma unroll
    for (int p = 0; p < 4; ++p) {
        int task = p * 256 + t;
        int kr = task >> 4;
        int nc = (task & 15) << 2;
        float4 v = *(const float4*)(Wp + (size_t)(kt * 64 + kr) * H_ + nt * 64 + nc);
        tile[kr * 68 + nc + 0] = f2bf(v.x);
        tile[kr * 68 + nc + 1] = f2bf(v.y);
        tile[kr * 68 + nc + 2] = f2bf(v.z);
        tile[kr * 68 + nc + 3] = f2bf(v.w);
    }
    __syncthreads();

    unsigned short* WTp = WT + ((size_t)c << 22);
#pragma unroll
    for (int q = 0; q < 2; ++q) {
        int task = q * 256 + t;
        int nl = task >> 3;
        int ko = (task & 7) << 3;
        u16x8 o;
#pragma unroll
        for (int j = 0; j < 8; ++j) o[j] = tile[(ko + j) * 68 + nl];
        *(u16x8*)(WTp + (size_t)(nt * 64 + nl) * K_ + kt * 64 + ko) = o;
    }
}

// ---------------------------------------------------------------------------
// Batched GEMM, deep-pipelined 256x256 tile:
//   BK=32, 8 waves (2Mx4N), per-wave 128x64 (acc 8x4 of 16x16 frags)
//   4-deep LDS ring (128 KiB), prefetch 3 K-tiles ahead (global_load_lds w=16)
//   ONE s_barrier + ONE counted s_waitcnt vmcnt(8) per K-tile (T3+T4)
//   slot XOR-swizzle (T2, derived): phys_slot = slot ^ ((row>>2)&3), applied
//   on the pre-swizzled global source AND the ds_read address (m173 pattern)
//   setprio around MFMA cluster (T5); operand-swapped MFMA -> f32x4 stores
__global__ __launch_bounds__(512, 2) void gemm2_kernel(
    const unsigned short* __restrict__ xb,   // [B][S][K] bf16
    const unsigned short* __restrict__ WT,   // [C][H][K] bf16
    const float* __restrict__ bias,          // [C][H]
    const int* __restrict__ cat,             // [B]
    float* __restrict__ out)                 // [B][S][H]
{
    extern __shared__ __align__(16) char smem[];   // 4 bufs x (A 16K | B 16K)

    const int t    = threadIdx.x;
    const int lane = t & 63;
    const int w    = t >> 6;            // 0..7
    const int wm   = w >> 2;            // 0..1
    const int wn   = w & 3;             // 0..3
    const int lo   = lane & 15;
    const int hi   = lane >> 4;         // 0..3

    // XCD-aware bijective swizzle (2048 % 8 == 0)
    const int wg = (blockIdx.x & 7) * 256 + (blockIdx.x >> 3);
    const int bn = wg & 15;
    const int bm = (wg >> 4) & 1;
    const int bb = wg >> 5;

    const int c = cat[bb];

    const unsigned short* Ap = xb + (size_t)bb * (S_ * K_) + (size_t)(bm * 256) * K_;
    const unsigned short* Bp = WT + (size_t)c * ((size_t)H_ * K_) + (size_t)(bn * 256) * K_;

    // staging: chunk ch = i*8+w covers rows [ch*16, ch*16+16), 64B per row.
    // linear LDS dest (row = ch*16 + lane>>2, slot = lane&3); global source
    // pre-swizzled: logical k-slot = (lane&3) ^ ((row>>2)&3) = (lane&3) ^ hi.
    const int srow  = lane >> 2;
    const int sslot = (lane & 3) ^ hi;
    const char* srcA[2]; const char* srcB[2];
    int offA[2], offB[2];
#pragma unroll
    for (int i = 0; i < 2; ++i) {
        int ch = i * 8 + w;
        int r  = ch * 16 + srow;
        srcA[i] = (const char*)(Ap + (size_t)r * K_ + sslot * 8);
        srcB[i] = (const char*)(Bp + (size_t)r * K_ + sslot * 8);
        offA[i] = ch * 1024;
        offB[i] = 16384 + ch * 1024;
    }

    // fragment read offsets: row stride 64B, swizzled slot = hi ^ ((row>>2)&3);
    // (row>>2)&3 == (lo>>2)&3 for all frags (16-row frag stride)
    const int xslot = (hi ^ ((lo >> 2) & 3)) << 4;
    int aoff[8], boff[4];
#pragma unroll
    for (int mi = 0; mi < 8; ++mi) aoff[mi] = (wm * 128 + mi * 16 + lo) * 64 + xslot;
#pragma unroll
    for (int ni = 0; ni < 4; ++ni) boff[ni] = 16384 + (wn * 64 + ni * 16 + lo) * 64 + xslot;

    f32x4 acc[8][4];
#pragma unroll
    for (int mi = 0; mi < 8; ++mi)
#pragma unroll
        for (int ni = 0; ni < 4; ++ni) acc[mi][ni] = f32x4{0.f, 0.f, 0.f, 0.f};

#define STAGE(s_, d_) do {                                                        \
    const int s__ = (s_);                                                         \
    char* dst__ = smem + (d_) * 32768;                                            \
    __builtin_amdgcn_global_load_lds((as1u32*)(srcA[0] + s__ * 64),               \
                                     (as3u32*)(dst__ + offA[0]), 16, 0, 0);       \
    __builtin_amdgcn_global_load_lds((as1u32*)(srcB[0] + s__ * 64),               \
                                     (as3u32*)(dst__ + offB[0]), 16, 0, 0);       \
    __builtin_amdgcn_global_load_lds((as1u32*)(srcA[1] + s__ * 64),               \
                                     (as3u32*)(dst__ + offA[1]), 16, 0, 0);       \
    __builtin_amdgcn_global_load_lds((as1u32*)(srcB[1] + s__ * 64),               \
                                     (as3u32*)(dst__ + offB[1]), 16, 0, 0);       \
} while (0)

    // prologue: stage K-tiles 0,1,2 into ring slots 0,1,2 (12 vmem instrs)
    STAGE(0, 0); STAGE(1, 1); STAGE(2, 2);

    // main loop: 32 K-tiles. At tile tt entry, outstanding loads are at most
    // {tt (issued tt-3), tt+1 (tt-2), tt+2 (tt-1)}; vmcnt(8) drains the oldest
    // 4 (= tile tt's) while keeping up to 8 newer ones in flight. Tail tiles
    // wrap-stage tiles 0..2 again (harmless: their ring slots are dead) so the
    // vmcnt count stays uniform — no peeled epilogue needed.
#pragma unroll 4
    for (int tt = 0; tt < 32; ++tt) {
        asm volatile("s_waitcnt vmcnt(8)" ::: "memory");
        __builtin_amdgcn_s_barrier();
        asm volatile("" ::: "memory");

        STAGE((tt + 3) & 31, (tt + 3) & 3);

        const char* buf = smem + (tt & 3) * 32768;
        bf16x8 av[8], bv[4];
#pragma unroll
        for (int mi = 0; mi < 8; ++mi) av[mi] = *(const bf16x8*)(buf + aoff[mi]);
#pragma unroll
        for (int ni = 0; ni < 4; ++ni) bv[ni] = *(const bf16x8*)(buf + boff[ni]);

        __builtin_amdgcn_s_setprio(1);
#pragma unroll
        for (int mi = 0; mi < 8; ++mi)
#pragma unroll
            for (int ni = 0; ni < 4; ++ni)
                acc[mi][ni] = __builtin_amdgcn_mfma_f32_16x16x32_bf16(
                    bv[ni], av[mi], acc[mi][ni], 0, 0, 0);
        __builtin_amdgcn_s_setprio(0);
    }
#undef STAGE

    // drain wrap-staged loads before LDS deallocation / endpgm
    asm volatile("s_waitcnt vmcnt(0)" ::: "memory");

    // epilogue. Operand-swapped D layout: n = frag_base + hi*4 + reg, m = lo.
    float* outp = out + ((size_t)bb * S_ + bm * 256 + wm * 128) * H_ + bn * 256 + wn * 64;
    const float* bp = bias + (size_t)c * H_ + bn * 256 + wn * 64;
#pragma unroll
    for (int ni = 0; ni < 4; ++ni) {
        const int nf = ni * 16 + hi * 4;
        const f32x4 b4 = *(const f32x4*)(bp + nf);
#pragma unroll
        for (int mi = 0; mi < 8; ++mi) {
            const int mf = mi * 16 + lo;
            f32x4 v = acc[mi][ni];
            v.x += b4.x; v.y += b4.y; v.z += b4.z; v.w += b4.w;
            *(f32x4*)(outp + (size_t)mf * H_ + nf) = v;
        }
    }
}

// ---------------------------------------------------------------------------
// Fallback (ws too small): correct but slow f32 vector-ALU kernel.
__global__ __launch_bounds__(256) void fallback_kernel(
    const float* __restrict__ x, const int* __restrict__ cat,
    const float* __restrict__ W, const float* __restrict__ bias,
    float* __restrict__ out)
{
    __shared__ float xs[K_];
    int bs = blockIdx.x;
    int bb = bs >> 9;
    int c  = cat[bb];
    const float* xp = x + (size_t)bs * K_;
    for (int i = threadIdx.x; i < K_ / 4; i += 256)
        ((float4*)xs)[i] = ((const float4*)xp)[i];
    __syncthreads();

    int h = blockIdx.y * 1024 + threadIdx.x * 4;
    const float* Wp = W + (size_t)c * K_ * H_ + h;
    float a0 = 0.f, a1 = 0.f, a2 = 0.f, a3 = 0.f;
    for (int k = 0; k < K_; ++k) {
        float xv = xs[k];
        float4 wv = *(const float4*)(Wp + (size_t)k * H_);
        a0 += xv * wv.x; a1 += xv * wv.y; a2 += xv * wv.z; a3 += xv * wv.w;
    }
    float4 bv = *(const float4*)(bias + c * H_ + h);
    float4 o; o.x = a0 + bv.x; o.y = a1 + bv.y; o.z = a2 + bv.z; o.w = a3 + bv.w;
    *(float4*)(out + (size_t)bs * H_ + h) = o;
}

// ---------------------------------------------------------------------------
extern "C" void kernel_launch(void* const* d_in, const int* in_sizes, int n_in,
                              void* d_out, int out_size, void* d_ws, size_t ws_size,
                              hipStream_t stream) {
    const float* x        = (const float*)d_in[0];
    const void*  cat_raw  = d_in[1];
    const float* W        = (const float*)d_in[2];
    const float* bias     = (const float*)d_in[3];
    float*       out      = (float*)d_out;

    const size_t CAT_BYTES = 256;
    const size_t XB_OFF    = 256;
    const size_t XB_BYTES  = (size_t)B_ * S_ * K_ * 2;          // 64 MiB
    const size_t WT_OFF    = XB_OFF + XB_BYTES;
    const size_t WT_BYTES  = (size_t)C_ * H_ * K_ * 2;          // 256 MiB
    const size_t NEED      = WT_OFF + WT_BYTES;

    const int* catp;
    if (ws_size >= CAT_BYTES) {
        int* cat32 = (int*)d_ws;
        fix_cat_kernel<<<1, 64, 0, stream>>>(cat_raw, cat32);
        catp = cat32;
    } else {
        catp = (const int*)cat_raw;
    }

    if (ws_size >= NEED) {
        unsigned short* xb = (unsigned short*)((char*)d_ws + XB_OFF);
        unsigned short* WT = (unsigned short*)((char*)d_ws + WT_OFF);
        cvt_x_kernel<<<2048, 256, 0, stream>>>((const float4*)x, (uint4*)xb,
                                               (int)((size_t)B_ * S_ * K_ / 8));
        dim3 gw(64, 16, 32);
        cvt_w_kernel<<<gw, 256, 0, stream>>>(W, WT);
        hipFuncSetAttribute((const void*)gemm2_kernel,
                            hipFuncAttributeMaxDynamicSharedMemorySize, 131072);
        gemm2_kernel<<<2048, 512, 131072, stream>>>(xb, WT, bias, catp, out);
    } else {
        dim3 g(B_ * S_, H_ / 1024);
        fallback_kernel<<<g, 256, 0, stream>>>(x, catp, W, bias, out);
    }
}